// Round 2
// baseline (1051.760 us; speedup 1.0000x reference)
//
#include <hip/hip_runtime.h>
#include <cmath>

// SSIM over (32,3,512,512) f32 pairs, 11x11 separable gaussian, valid conv,
// scalar mean output. Round 2: horizontal pass from registers (no input LDS
// staging), b128 LDS writes, 8-rows-per-thread vertical pass, in-kernel
// finalize via atomic block counter.

#define HH 512
#define WW 512
#define OH 502           // 512 - 11 + 1
#define OW 502
#define NC 96            // 32 * 3
#define TX 32            // output tile cols
#define TY 32            // output tile rows
#define INR 42           // h rows per tile (TY + 10)
#define HPAD 36          // row stride (floats) for h arrays
#define GXD 16
#define GYD 16
#define NBLK (GXD * GYD * NC)

struct GaussW { float g[11]; };

__global__ __launch_bounds__(256, 5) void ssim_kernel(
        const float* __restrict__ X, const float* __restrict__ Y,
        double* __restrict__ acc, unsigned int* __restrict__ cnt,
        float* __restrict__ out, GaussW gw) {
    // 5 horizontal-conv maps: x, y, x*x, y*y, x*y (normalized inputs).
    // 5*42*36*4 = 30240 B -> 5 blocks/CU (LDS-capped), 20 waves/CU.
    __shared__ float h[5][INR][HPAD];
    __shared__ double wsum[2];

    const int tid = threadIdx.x;
    const int R0 = blockIdx.y * TY;
    const int C0 = blockIdx.x * TX;
    const float* Xp = X + (size_t)blockIdx.z * (HH * WW);
    const float* Yp = Y + (size_t)blockIdx.z * (HH * WW);
    const bool edge = (blockIdx.x == GXD - 1);   // loads would run past row end

    // ---- Phase A: horizontal 11-tap conv, 42 rows x 32 cols, 4 cols/thread.
    // Inputs come straight from global (float4); L1/L2 absorb the 3x overlap.
    for (int task = tid; task < INR * 8; task += 256) {
        const int r  = task >> 3;
        const int c0 = (task & 7) * 4;
        const int gr = min(R0 + r, HH - 1);      // clamp feeds discarded rows only
        const float* xrow = Xp + gr * WW;
        const float* yrow = Yp + gr * WW;
        const int gc = C0 + c0;                  // multiple of 4 -> aligned

        float xv[16], yv[16];
        if (!edge) {
            const float4* x4 = (const float4*)(xrow + gc);
            const float4* y4 = (const float4*)(yrow + gc);
            float4 a0 = x4[0], a1 = x4[1], a2 = x4[2], a3 = x4[3];
            float4 b0 = y4[0], b1 = y4[1], b2 = y4[2], b3 = y4[3];
            xv[0]=a0.x; xv[1]=a0.y; xv[2]=a0.z; xv[3]=a0.w;
            xv[4]=a1.x; xv[5]=a1.y; xv[6]=a1.z; xv[7]=a1.w;
            xv[8]=a2.x; xv[9]=a2.y; xv[10]=a2.z; xv[11]=a2.w;
            xv[12]=a3.x; xv[13]=a3.y; xv[14]=a3.z; xv[15]=a3.w;
            yv[0]=b0.x; yv[1]=b0.y; yv[2]=b0.z; yv[3]=b0.w;
            yv[4]=b1.x; yv[5]=b1.y; yv[6]=b1.z; yv[7]=b1.w;
            yv[8]=b2.x; yv[9]=b2.y; yv[10]=b2.z; yv[11]=b2.w;
            yv[12]=b3.x; yv[13]=b3.y; yv[14]=b3.z; yv[15]=b3.w;
        } else {
            #pragma unroll
            for (int i = 0; i < 16; ++i) {       // clamped cols feed discarded
                int c = min(gc + i, WW - 1);     // outputs only (c >= 502)
                xv[i] = xrow[c];
                yv[i] = yrow[c];
            }
        }

        float ax[4]  = {0.f,0.f,0.f,0.f};
        float ay[4]  = {0.f,0.f,0.f,0.f};
        float axx[4] = {0.f,0.f,0.f,0.f};
        float ayy[4] = {0.f,0.f,0.f,0.f};
        float axy[4] = {0.f,0.f,0.f,0.f};
        // element-major: 3 products live at a time -> low VGPR pressure
        #pragma unroll
        for (int k = 0; k < 14; ++k) {
            float px = fmaf(xv[k], 0.5f, 0.5f);  // normalize [-1,1]->[0,1]
            float py = fmaf(yv[k], 0.5f, 0.5f);
            float pxx = px * px, pyy = py * py, pxy = px * py;
            #pragma unroll
            for (int j = 0; j < 4; ++j) {
                int t = k - j;
                if (t >= 0 && t < 11) {          // statically resolved
                    float g = gw.g[t];
                    ax[j]  = fmaf(g, px,  ax[j]);
                    ay[j]  = fmaf(g, py,  ay[j]);
                    axx[j] = fmaf(g, pxx, axx[j]);
                    ayy[j] = fmaf(g, pyy, ayy[j]);
                    axy[j] = fmaf(g, pxy, axy[j]);
                }
            }
        }
        // b128 writes; row base 144 B -> 16B-aligned; structurally conflict-free
        *(float4*)&h[0][r][c0] = make_float4(ax[0],  ax[1],  ax[2],  ax[3]);
        *(float4*)&h[1][r][c0] = make_float4(ay[0],  ay[1],  ay[2],  ay[3]);
        *(float4*)&h[2][r][c0] = make_float4(axx[0], axx[1], axx[2], axx[3]);
        *(float4*)&h[3][r][c0] = make_float4(ayy[0], ayy[1], ayy[2], ayy[3]);
        *(float4*)&h[4][r][c0] = make_float4(axy[0], axy[1], axy[2], axy[3]);
    }
    __syncthreads();

    // ---- Phase B: vertical 11-tap conv + SSIM. 128 threads, 1 col x 8 rows.
    // Wave reads one row across c=0..31 twice (2 lanes/bank = free).
    double tsum = 0.0;
    if (tid < 128) {
        const int c  = tid & 31;
        const int rb = (tid >> 5) * 8;           // 0,8,16,24
        float m1[8], m2[8], e11[8], e22[8], e12[8];
        #pragma unroll
        for (int j = 0; j < 8; ++j) { m1[j]=0.f; m2[j]=0.f; e11[j]=0.f; e22[j]=0.f; e12[j]=0.f; }
        #pragma unroll
        for (int k = 0; k < 18; ++k) {           // rows rb..rb+17 feed rb..rb+7
            float v0 = h[0][rb + k][c];
            float v1 = h[1][rb + k][c];
            float v2 = h[2][rb + k][c];
            float v3 = h[3][rb + k][c];
            float v4 = h[4][rb + k][c];
            #pragma unroll
            for (int j = 0; j < 8; ++j) {
                int t = k - j;
                if (t >= 0 && t < 11) {
                    float g = gw.g[t];
                    m1[j]  = fmaf(g, v0, m1[j]);
                    m2[j]  = fmaf(g, v1, m2[j]);
                    e11[j] = fmaf(g, v2, e11[j]);
                    e22[j] = fmaf(g, v3, e22[j]);
                    e12[j] = fmaf(g, v4, e12[j]);
                }
            }
        }
        const float C1 = 1.0e-4f;
        const float C2 = 9.0e-4f;
        #pragma unroll
        for (int j = 0; j < 8; ++j) {
            int gr = R0 + rb + j, gc = C0 + c;
            if (gr < OH && gc < OW) {
                float mu1 = m1[j], mu2 = m2[j];
                float m11 = mu1*mu1, m22 = mu2*mu2, m12 = mu1*mu2;
                float s1  = e11[j] - m11;
                float s2  = e22[j] - m22;
                float s12 = e12[j] - m12;
                float cs  = (2.0f*s12 + C2) / (s1 + s2 + C2);
                float sm  = ((2.0f*m12 + C1) / (m11 + m22 + C1)) * cs;
                tsum += (double)sm;
            }
        }
    }

    // block reduction (double) + one f64 atomic; last block finalizes
    #pragma unroll
    for (int off = 32; off > 0; off >>= 1)
        tsum += __shfl_down(tsum, off, 64);
    if ((tid & 63) == 0 && tid < 128) wsum[tid >> 6] = tsum;
    __syncthreads();
    if (tid == 0) {
        atomicAdd(acc, wsum[0] + wsum[1]);
        __threadfence();
        unsigned int old = atomicAdd(cnt, 1u);
        if (old == (unsigned int)(NBLK - 1)) {   // all blocks' adds are visible
            double v = atomicAdd(acc, 0.0);      // coherent device-scope read
            out[0] = (float)(v * (1.0 / (double)((long long)NC * OH * OW)));
        }
    }
}

extern "C" void kernel_launch(void* const* d_in, const int* in_sizes, int n_in,
                              void* d_out, int out_size, void* d_ws, size_t ws_size,
                              hipStream_t stream) {
    const float* X = (const float*)d_in[0];
    const float* Y = (const float*)d_in[1];
    float* out = (float*)d_out;
    double* acc = (double*)d_ws;
    unsigned int* cnt = (unsigned int*)((char*)d_ws + sizeof(double));

    // d_ws is re-poisoned to 0xAA before every timed launch: zero acc + cnt.
    hipMemsetAsync(d_ws, 0, 16, stream);

    // Gaussian weights (win=11, sigma=1.5), computed in f64, passed by value.
    GaussW gw;
    {
        double g[11], s = 0.0;
        for (int i = 0; i < 11; ++i) {
            double d = (double)(i - 5);
            g[i] = exp(-d * d / (2.0 * 1.5 * 1.5));
            s += g[i];
        }
        for (int i = 0; i < 11; ++i) gw.g[i] = (float)(g[i] / s);
    }

    dim3 grid(GXD, GYD, NC);
    ssim_kernel<<<grid, dim3(256), 0, stream>>>(X, Y, acc, cnt, out, gw);
}

// Round 3
// 329.268 us; speedup vs baseline: 3.1942x; 3.1942x over previous
//
#include <hip/hip_runtime.h>
#include <cmath>

// SSIM over (32,3,512,512) f32 pairs, 11x11 separable gaussian, valid conv,
// scalar mean output. Round 3: no __threadfence (R2's 3x regression was the
// per-block agent-fence L2 writeback), separate finalize dispatch, 4 LDS maps
// instead of 5 (sigma1^2+sigma2^2 only ever used as a sum -> convolve x^2+y^2),
// all 256 threads in the vertical pass, atomics spread over 64 slots.

#define HH 512
#define WW 512
#define OH 502           // 512 - 11 + 1
#define OW 502
#define NC 96            // 32 * 3
#define TX 32            // output tile cols
#define TY 32            // output tile rows
#define INR 42           // h rows per tile (TY + 10)
#define HPAD 36          // row stride (floats) for h arrays
#define GXD 16
#define GYD 16
#define NSLOT 64         // f64 accumulator slots, 64B apart

struct GaussW { float g[11]; };

__global__ __launch_bounds__(256, 6) void ssim_kernel(
        const float* __restrict__ X, const float* __restrict__ Y,
        double* __restrict__ acc, GaussW gw) {
    // 4 horizontal-conv maps: x, y, x*x+y*y, x*y (normalized inputs).
    // 4*42*36*4 = 24192 B -> 6 blocks/CU (LDS-capped), 24 waves/CU.
    __shared__ float h[4][INR][HPAD];
    __shared__ double wsum[4];

    const int tid = threadIdx.x;
    const int R0 = blockIdx.y * TY;
    const int C0 = blockIdx.x * TX;
    const float* Xp = X + (size_t)blockIdx.z * (HH * WW);
    const float* Yp = Y + (size_t)blockIdx.z * (HH * WW);
    const bool edge = (blockIdx.x == GXD - 1);   // loads would run past row end

    // ---- Phase A: horizontal 11-tap conv, 42 rows x 32 cols, 4 cols/thread.
    // Inputs straight from global (float4); L1/L2 absorb the 3x window overlap.
    for (int task = tid; task < INR * 8; task += 256) {
        const int r  = task >> 3;
        const int c0 = (task & 7) * 4;
        const int gr = min(R0 + r, HH - 1);      // clamp feeds discarded rows only
        const float* xrow = Xp + gr * WW;
        const float* yrow = Yp + gr * WW;
        const int gc = C0 + c0;                  // multiple of 4 -> aligned

        float xv[16], yv[16];
        if (!edge) {
            const float4* x4 = (const float4*)(xrow + gc);
            const float4* y4 = (const float4*)(yrow + gc);
            float4 a0 = x4[0], a1 = x4[1], a2 = x4[2], a3 = x4[3];
            float4 b0 = y4[0], b1 = y4[1], b2 = y4[2], b3 = y4[3];
            xv[0]=a0.x; xv[1]=a0.y; xv[2]=a0.z; xv[3]=a0.w;
            xv[4]=a1.x; xv[5]=a1.y; xv[6]=a1.z; xv[7]=a1.w;
            xv[8]=a2.x; xv[9]=a2.y; xv[10]=a2.z; xv[11]=a2.w;
            xv[12]=a3.x; xv[13]=a3.y; xv[14]=a3.z; xv[15]=a3.w;
            yv[0]=b0.x; yv[1]=b0.y; yv[2]=b0.z; yv[3]=b0.w;
            yv[4]=b1.x; yv[5]=b1.y; yv[6]=b1.z; yv[7]=b1.w;
            yv[8]=b2.x; yv[9]=b2.y; yv[10]=b2.z; yv[11]=b2.w;
            yv[12]=b3.x; yv[13]=b3.y; yv[14]=b3.z; yv[15]=b3.w;
        } else {
            #pragma unroll
            for (int i = 0; i < 16; ++i) {       // clamped cols feed discarded
                int c = min(gc + i, WW - 1);     // outputs only (c >= 502)
                xv[i] = xrow[c];
                yv[i] = yrow[c];
            }
        }

        float a1c[4] = {0.f,0.f,0.f,0.f};        // conv_h(x)
        float a2c[4] = {0.f,0.f,0.f,0.f};        // conv_h(y)
        float asc[4] = {0.f,0.f,0.f,0.f};        // conv_h(x*x + y*y)
        float apc[4] = {0.f,0.f,0.f,0.f};        // conv_h(x*y)
        #pragma unroll
        for (int k = 0; k < 14; ++k) {
            float px = fmaf(xv[k], 0.5f, 0.5f);  // normalize [-1,1]->[0,1]
            float py = fmaf(yv[k], 0.5f, 0.5f);
            float ps = fmaf(py, py, px * px);    // px^2 + py^2
            float pp = px * py;
            #pragma unroll
            for (int j = 0; j < 4; ++j) {
                int t = k - j;
                if (t >= 0 && t < 11) {          // statically resolved
                    float g = gw.g[t];
                    a1c[j] = fmaf(g, px, a1c[j]);
                    a2c[j] = fmaf(g, py, a2c[j]);
                    asc[j] = fmaf(g, ps, asc[j]);
                    apc[j] = fmaf(g, pp, apc[j]);
                }
            }
        }
        // b128 writes; row base 144 B -> 16B-aligned; conflict-free pattern
        *(float4*)&h[0][r][c0] = make_float4(a1c[0], a1c[1], a1c[2], a1c[3]);
        *(float4*)&h[1][r][c0] = make_float4(a2c[0], a2c[1], a2c[2], a2c[3]);
        *(float4*)&h[2][r][c0] = make_float4(asc[0], asc[1], asc[2], asc[3]);
        *(float4*)&h[3][r][c0] = make_float4(apc[0], apc[1], apc[2], apc[3]);
    }
    __syncthreads();

    // ---- Phase B: vertical 11-tap conv + SSIM. 256 threads, 1 col x 4 rows.
    // Wave spans 2 rows x 32 cols -> 2 lanes/bank = free (m136).
    const int c  = tid & 31;
    const int rb = (tid >> 5) * 4;               // 0,4,...,28
    float m1[4]  = {0.f,0.f,0.f,0.f};
    float m2[4]  = {0.f,0.f,0.f,0.f};
    float es[4]  = {0.f,0.f,0.f,0.f};
    float ep[4]  = {0.f,0.f,0.f,0.f};
    #pragma unroll
    for (int k = 0; k < 14; ++k) {               // rows rb..rb+13 feed rb..rb+3
        float v0 = h[0][rb + k][c];
        float v1 = h[1][rb + k][c];
        float v2 = h[2][rb + k][c];
        float v3 = h[3][rb + k][c];
        #pragma unroll
        for (int j = 0; j < 4; ++j) {
            int t = k - j;
            if (t >= 0 && t < 11) {
                float g = gw.g[t];
                m1[j] = fmaf(g, v0, m1[j]);
                m2[j] = fmaf(g, v1, m2[j]);
                es[j] = fmaf(g, v2, es[j]);
                ep[j] = fmaf(g, v3, ep[j]);
            }
        }
    }

    const float C1 = 1.0e-4f;
    const float C2 = 9.0e-4f;
    double tsum = 0.0;
    #pragma unroll
    for (int j = 0; j < 4; ++j) {
        int gr = R0 + rb + j, gc = C0 + c;
        if (gr < OH && gc < OW) {
            float mu1 = m1[j], mu2 = m2[j];
            float mA  = fmaf(mu2, mu2, mu1 * mu1);   // mu1^2 + mu2^2
            float m12 = mu1 * mu2;
            float s12 = ep[j] - m12;                 // sigma12
            float sS  = es[j] - mA;                  // sigma1^2 + sigma2^2
            float num = (2.0f * m12 + C1) * (2.0f * s12 + C2);
            float den = (mA + C1) * (sS + C2);
            tsum += (double)(num / den);
        }
    }

    // block reduction (double) + one f64 atomic into a strided slot
    #pragma unroll
    for (int off = 32; off > 0; off >>= 1)
        tsum += __shfl_down(tsum, off, 64);
    if ((tid & 63) == 0) wsum[tid >> 6] = tsum;
    __syncthreads();
    if (tid == 0) {
        int slot = (blockIdx.x + blockIdx.y * GXD + blockIdx.z * GXD * GYD) & (NSLOT - 1);
        atomicAdd(&acc[slot * 8], wsum[0] + wsum[1] + wsum[2] + wsum[3]);
    }
}

__global__ void ssim_finalize(const double* __restrict__ acc,
                              float* __restrict__ out) {
    int lane = threadIdx.x;                      // 64 threads, one slot each
    double t = acc[lane * 8];
    #pragma unroll
    for (int off = 32; off > 0; off >>= 1)
        t += __shfl_down(t, off, 64);
    if (lane == 0)
        out[0] = (float)(t * (1.0 / (double)((long long)NC * OH * OW)));
}

extern "C" void kernel_launch(void* const* d_in, const int* in_sizes, int n_in,
                              void* d_out, int out_size, void* d_ws, size_t ws_size,
                              hipStream_t stream) {
    const float* X = (const float*)d_in[0];
    const float* Y = (const float*)d_in[1];
    float* out = (float*)d_out;
    double* acc = (double*)d_ws;                 // 64 slots x 64 B = 4 KB

    // d_ws is re-poisoned to 0xAA before every timed launch: zero the slots.
    hipMemsetAsync(d_ws, 0, NSLOT * 64, stream);

    // Gaussian weights (win=11, sigma=1.5), computed in f64, passed by value.
    GaussW gw;
    {
        double g[11], s = 0.0;
        for (int i = 0; i < 11; ++i) {
            double d = (double)(i - 5);
            g[i] = exp(-d * d / (2.0 * 1.5 * 1.5));
            s += g[i];
        }
        for (int i = 0; i < 11; ++i) gw.g[i] = (float)(g[i] / s);
    }

    dim3 grid(GXD, GYD, NC);
    ssim_kernel<<<grid, dim3(256), 0, stream>>>(X, Y, acc, gw);
    ssim_finalize<<<1, dim3(64), 0, stream>>>(acc, out);
}

// Round 4
// 321.839 us; speedup vs baseline: 3.2680x; 1.0231x over previous
//
#include <hip/hip_runtime.h>
#include <cmath>

// SSIM over (32,3,512,512) f32 pairs, 11x11 separable gaussian, valid conv,
// scalar mean output. Round 4: pack the 4 conv maps (x, y, x^2+y^2, x*y) into
// float4 lanes -> v_pk_fma_f32 (2 FMA/issue) and 1 ds_read_b128 per tap-row;
// convolve raw inputs (normalization folded into epilogue since sum(g)=1);
// single f32 divide per thread via common-denominator combine.

#define HH 512
#define WW 512
#define OH 502           // 512 - 11 + 1
#define OW 502
#define NC 96            // 32 * 3
#define TX 32            // output tile cols
#define TY 32            // output tile rows
#define INR 42           // h rows per tile (TY + 10)
#define HP4 33           // row stride in float4s (528 B -> 4-bank row skew)
#define GXD 16
#define GYD 16
#define NSLOT 64         // f64 accumulator slots, 64 B apart

typedef float f4 __attribute__((ext_vector_type(4)));

struct GaussW { float g[11]; };

static __device__ __forceinline__ f4 sp(float s) { return (f4){s, s, s, s}; }

__global__ __launch_bounds__(256, 6) void ssim_kernel(
        const float* __restrict__ X, const float* __restrict__ Y,
        double* __restrict__ acc, GaussW gw) {
    // h[r][c] = float4(conv_h(x), conv_h(y), conv_h(x^2+y^2), conv_h(x*y)),
    // raw domain. 42*33*16 = 22176 B -> 6+ blocks/CU.
    __shared__ f4 hS[INR][HP4];
    __shared__ double wsum[4];

    const int tid = threadIdx.x;
    const int R0 = blockIdx.y * TY;
    const int C0 = blockIdx.x * TX;
    const float* Xp = X + (size_t)blockIdx.z * (HH * WW);
    const float* Yp = Y + (size_t)blockIdx.z * (HH * WW);
    const bool edge = (blockIdx.x == GXD - 1);   // loads would run past row end

    // ---- Phase A: horizontal 11-tap conv, 42 rows x 32 cols, 4 cols/thread.
    for (int task = tid; task < INR * 8; task += 256) {
        const int r  = task >> 3;
        const int c0 = (task & 7) * 4;
        const int gr = min(R0 + r, HH - 1);      // clamp feeds discarded rows only
        const float* xrow = Xp + gr * WW;
        const float* yrow = Yp + gr * WW;
        const int gc = C0 + c0;                  // multiple of 4 -> aligned

        float xv[16], yv[16];
        if (!edge) {
            const float4* x4 = (const float4*)(xrow + gc);
            const float4* y4 = (const float4*)(yrow + gc);
            float4 a0 = x4[0], a1 = x4[1], a2 = x4[2], a3 = x4[3];
            float4 b0 = y4[0], b1 = y4[1], b2 = y4[2], b3 = y4[3];
            xv[0]=a0.x; xv[1]=a0.y; xv[2]=a0.z; xv[3]=a0.w;
            xv[4]=a1.x; xv[5]=a1.y; xv[6]=a1.z; xv[7]=a1.w;
            xv[8]=a2.x; xv[9]=a2.y; xv[10]=a2.z; xv[11]=a2.w;
            xv[12]=a3.x; xv[13]=a3.y; xv[14]=a3.z; xv[15]=a3.w;
            yv[0]=b0.x; yv[1]=b0.y; yv[2]=b0.z; yv[3]=b0.w;
            yv[4]=b1.x; yv[5]=b1.y; yv[6]=b1.z; yv[7]=b1.w;
            yv[8]=b2.x; yv[9]=b2.y; yv[10]=b2.z; yv[11]=b2.w;
            yv[12]=b3.x; yv[13]=b3.y; yv[14]=b3.z; yv[15]=b3.w;
        } else {
            #pragma unroll
            for (int i = 0; i < 16; ++i) {       // clamped cols feed discarded
                int c = min(gc + i, WW - 1);     // outputs only (c >= 502)
                xv[i] = xrow[c];
                yv[i] = yrow[c];
            }
        }

        f4 a0v = sp(0.f), a1v = sp(0.f), a2v = sp(0.f), a3v = sp(0.f);
        #pragma unroll
        for (int k = 0; k < 14; ++k) {
            float x = xv[k], y = yv[k];
            f4 P;
            P.x = x; P.y = y;
            P.z = fmaf(x, x, y * y);             // x^2 + y^2 (raw domain)
            P.w = x * y;
            #pragma unroll
            for (int j = 0; j < 4; ++j) {
                int t = k - j;
                if (t >= 0 && t < 11) {          // statically resolved
                    f4 G = sp(gw.g[t]);
                    if (j == 0) a0v = __builtin_elementwise_fma(G, P, a0v);
                    if (j == 1) a1v = __builtin_elementwise_fma(G, P, a1v);
                    if (j == 2) a2v = __builtin_elementwise_fma(G, P, a2v);
                    if (j == 3) a3v = __builtin_elementwise_fma(G, P, a3v);
                }
            }
        }
        hS[r][c0 + 0] = a0v;                     // ds_write_b128, conflict-free
        hS[r][c0 + 1] = a1v;
        hS[r][c0 + 2] = a2v;
        hS[r][c0 + 3] = a3v;
    }
    __syncthreads();

    // ---- Phase B: vertical 11-tap conv + SSIM. 256 threads, 1 col x 4 rows.
    const int c  = tid & 31;
    const int rb = (tid >> 5) * 4;               // 0,4,...,28
    f4 b0v = sp(0.f), b1v = sp(0.f), b2v = sp(0.f), b3v = sp(0.f);
    #pragma unroll
    for (int k = 0; k < 14; ++k) {               // rows rb..rb+13 feed rb..rb+3
        f4 v = hS[rb + k][c];                    // one ds_read_b128 per tap-row
        #pragma unroll
        for (int j = 0; j < 4; ++j) {
            int t = k - j;
            if (t >= 0 && t < 11) {
                f4 G = sp(gw.g[t]);
                if (j == 0) b0v = __builtin_elementwise_fma(G, v, b0v);
                if (j == 1) b1v = __builtin_elementwise_fma(G, v, b1v);
                if (j == 2) b2v = __builtin_elementwise_fma(G, v, b2v);
                if (j == 3) b3v = __builtin_elementwise_fma(G, v, b3v);
            }
        }
    }

    // Epilogue: raw-domain fixup. With u=(x+1)/2: mu1=(cx+1)/2,
    // sigma1^2+sigma2^2 = (cs - cx^2 - cy^2)/4, sigma12 = (cp - cx*cy)/4.
    const float C1 = 1.0e-4f;
    const float C2 = 9.0e-4f;
    float nn[4], dd[4];
    #pragma unroll
    for (int j = 0; j < 4; ++j) {
        f4 v = (j == 0) ? b0v : (j == 1) ? b1v : (j == 2) ? b2v : b3v;
        float t1 = v.x + 1.f, t2 = v.y + 1.f;    // 2*mu1, 2*mu2
        float num1 = fmaf(t1 * t2, 0.5f, C1);    // 2*mu1*mu2 + C1
        float den1 = fmaf(fmaf(t2, t2, t1 * t1), 0.25f, C1);
        float num2 = fmaf(v.w - v.x * v.y, 0.5f, C2);   // 2*sigma12 + C2
        float den2 = fmaf(v.z - fmaf(v.x, v.x, v.y * v.y), 0.25f, C2);
        bool valid = (R0 + rb + j < OH) & (C0 + c < OW);
        nn[j] = valid ? num1 * num2 : 0.f;
        dd[j] = valid ? den1 * den2 : 1.f;
    }
    // one divide for all 4 outputs: sum n_j/d_j over common denominator
    float dd01 = dd[0] * dd[1], dd23 = dd[2] * dd[3];
    float s01  = fmaf(nn[0], dd[1], nn[1] * dd[0]);
    float s23  = fmaf(nn[2], dd[3], nn[3] * dd[2]);
    double tsum = (double)(fmaf(s01, dd23, s23 * dd01) / (dd01 * dd23));

    // block reduction (double) + one f64 atomic into a strided slot
    #pragma unroll
    for (int off = 32; off > 0; off >>= 1)
        tsum += __shfl_down(tsum, off, 64);
    if ((tid & 63) == 0) wsum[tid >> 6] = tsum;
    __syncthreads();
    if (tid == 0) {
        int slot = (blockIdx.x + blockIdx.y * GXD + blockIdx.z * GXD * GYD) & (NSLOT - 1);
        atomicAdd(&acc[slot * 8], wsum[0] + wsum[1] + wsum[2] + wsum[3]);
    }
}

__global__ void ssim_finalize(const double* __restrict__ acc,
                              float* __restrict__ out) {
    int lane = threadIdx.x;                      // 64 threads, one slot each
    double t = acc[lane * 8];
    #pragma unroll
    for (int off = 32; off > 0; off >>= 1)
        t += __shfl_down(t, off, 64);
    if (lane == 0)
        out[0] = (float)(t * (1.0 / (double)((long long)NC * OH * OW)));
}

extern "C" void kernel_launch(void* const* d_in, const int* in_sizes, int n_in,
                              void* d_out, int out_size, void* d_ws, size_t ws_size,
                              hipStream_t stream) {
    const float* X = (const float*)d_in[0];
    const float* Y = (const float*)d_in[1];
    float* out = (float*)d_out;
    double* acc = (double*)d_ws;                 // 64 slots x 64 B = 4 KB

    // d_ws is re-poisoned to 0xAA before every timed launch: zero the slots.
    hipMemsetAsync(d_ws, 0, NSLOT * 64, stream);

    // Gaussian weights (win=11, sigma=1.5), computed in f64, passed by value.
    GaussW gw;
    {
        double g[11], s = 0.0;
        for (int i = 0; i < 11; ++i) {
            double d = (double)(i - 5);
            g[i] = exp(-d * d / (2.0 * 1.5 * 1.5));
            s += g[i];
        }
        for (int i = 0; i < 11; ++i) gw.g[i] = (float)(g[i] / s);
    }

    dim3 grid(GXD, GYD, NC);
    ssim_kernel<<<grid, dim3(256), 0, stream>>>(X, Y, acc, gw);
    ssim_finalize<<<1, dim3(64), 0, stream>>>(acc, out);
}

// Round 5
// 293.660 us; speedup vs baseline: 3.5816x; 1.0960x over previous
//
#include <hip/hip_runtime.h>
#include <cmath>

// SSIM over (32,3,512,512) f32 pairs, 11x11 separable gaussian, valid conv,
// scalar mean output. Round 5: tall-strip blocks (32 cols x 64 output rows),
// one Phase A fill of a 74-row f4 h-buffer + one Phase B consume; bit-swapped
// Phase-A task map makes ds_write_b128 conflict-free (R4's 1.24e7 conflict
// cycles == 21 writes/block x 24 cyc, exact); 8 rows/thread in Phase B
// (2.25 LDS reads/output vs 3.5); one f64 reduction per 2048 outputs.

#define HH 512
#define WW 512
#define OH 502           // 512 - 11 + 1
#define OW 502
#define NC 96            // 32 * 3
#define TXS 32           // strip width (output cols)
#define TYB 64           // band height (output rows)
#define INR 74           // h-buffer rows = TYB + 10
#define HP4 33           // row stride in float4s (528 B -> 4-bank row rotation)
#define GX 16
#define GY 8
#define NTASK (INR * 8)  // 592 Phase-A tasks (4 h-cols each)
#define NSLOT 64         // f64 accumulator slots, 64 B apart

typedef float f4 __attribute__((ext_vector_type(4)));

struct GaussW { float g[11]; };

static __device__ __forceinline__ f4 sp(float s) { return (f4){s, s, s, s}; }

__global__ __launch_bounds__(256, 4) void ssim_kernel(
        const float* __restrict__ X, const float* __restrict__ Y,
        double* __restrict__ acc, GaussW gw) {
    // hS[r][c] = f4(conv_h(x), conv_h(y), conv_h(x^2+y^2), conv_h(x*y)), raw
    // domain. 74*33*16 = 39072 B -> 4 blocks/CU.
    __shared__ f4 hS[INR][HP4];
    __shared__ double wsum[4];

    const int tid = threadIdx.x;
    const int R0 = blockIdx.y * TYB;
    const int C0 = blockIdx.x * TXS;
    const float* Xp = X + (size_t)blockIdx.z * (HH * WW);
    const float* Yp = Y + (size_t)blockIdx.z * (HH * WW);
    const bool edge = (blockIdx.x == GX - 1);    // reads would pass col 511

    // ---- Phase A: horizontal 11-tap conv, 74 rows x 32 cols, 4 cols/task.
    // Task map puts row in the LOW 3 bits: an 8-lane LDS service phase sees 8
    // different rows -> write banks 4*(r+q) disjoint -> conflict-free.
    for (int t = tid; t < NTASK; t += 256) {
        int r, cg;
        if (t < 576) { r = (t & 7) | ((t >> 6) << 3); cg = (t >> 3) & 7; }
        else         { int tt = t - 576; r = 72 + (tt & 1); cg = (tt >> 1) & 7; }
        const int gr = min(R0 + r, HH - 1);      // clamp feeds masked rows only
        const float* xrow = Xp + gr * WW;
        const float* yrow = Yp + gr * WW;
        const int gc = C0 + 4 * cg;              // f4-aligned

        float xv[16], yv[16];
        if (!edge) {
            const float4* x4 = (const float4*)(xrow + gc);
            const float4* y4 = (const float4*)(yrow + gc);
            float4 a0 = x4[0], a1 = x4[1], a2 = x4[2], a3 = x4[3];
            float4 b0 = y4[0], b1 = y4[1], b2 = y4[2], b3 = y4[3];
            xv[0]=a0.x; xv[1]=a0.y; xv[2]=a0.z; xv[3]=a0.w;
            xv[4]=a1.x; xv[5]=a1.y; xv[6]=a1.z; xv[7]=a1.w;
            xv[8]=a2.x; xv[9]=a2.y; xv[10]=a2.z; xv[11]=a2.w;
            xv[12]=a3.x; xv[13]=a3.y; xv[14]=a3.z; xv[15]=a3.w;
            yv[0]=b0.x; yv[1]=b0.y; yv[2]=b0.z; yv[3]=b0.w;
            yv[4]=b1.x; yv[5]=b1.y; yv[6]=b1.z; yv[7]=b1.w;
            yv[8]=b2.x; yv[9]=b2.y; yv[10]=b2.z; yv[11]=b2.w;
            yv[12]=b3.x; yv[13]=b3.y; yv[14]=b3.z; yv[15]=b3.w;
        } else {
            #pragma unroll
            for (int i = 0; i < 16; ++i) {       // clamped cols feed masked
                int c = min(gc + i, WW - 1);     // outputs only (c >= 502)
                xv[i] = xrow[c];
                yv[i] = yrow[c];
            }
        }

        f4 a0v = sp(0.f), a1v = sp(0.f), a2v = sp(0.f), a3v = sp(0.f);
        #pragma unroll
        for (int k = 0; k < 14; ++k) {
            float x = xv[k], y = yv[k];
            f4 P;
            P.x = x; P.y = y;
            P.z = fmaf(x, x, y * y);             // raw domain (sum(g)=1 lets
            P.w = x * y;                         // normalization fold into epi)
            #pragma unroll
            for (int j = 0; j < 4; ++j) {
                int u = k - j;
                if (u >= 0 && u < 11) {          // statically resolved
                    f4 G = sp(gw.g[u]);
                    if (j == 0) a0v = __builtin_elementwise_fma(G, P, a0v);
                    if (j == 1) a1v = __builtin_elementwise_fma(G, P, a1v);
                    if (j == 2) a2v = __builtin_elementwise_fma(G, P, a2v);
                    if (j == 3) a3v = __builtin_elementwise_fma(G, P, a3v);
                }
            }
        }
        hS[r][4 * cg + 0] = a0v;                 // conflict-free b128 writes
        hS[r][4 * cg + 1] = a1v;
        hS[r][4 * cg + 2] = a2v;
        hS[r][4 * cg + 3] = a3v;
    }
    __syncthreads();

    // ---- Phase B: vertical 11-tap conv + SSIM. 256 threads, 1 col x 8 rows.
    // Read: 8-lane phase shares a row, cols 0..7(+8m) -> banks 4(R+c) disjoint.
    const int c  = tid & 31;
    const int rb = (tid >> 5) * 8;               // 0,8,...,56
    f4 A[8];
    #pragma unroll
    for (int j = 0; j < 8; ++j) A[j] = sp(0.f);
    #pragma unroll
    for (int k = 0; k < 18; ++k) {               // rows rb..rb+17 feed rb..rb+7
        f4 v = hS[rb + k][c];                    // one ds_read_b128 per tap-row
        #pragma unroll
        for (int j = 0; j < 8; ++j) {
            int u = k - j;
            if (u >= 0 && u < 11) {
                f4 G = sp(gw.g[u]);
                A[j] = __builtin_elementwise_fma(G, v, A[j]);
            }
        }
    }

    // Epilogue: raw-domain fixup. With u=(x+1)/2: 2*mu = cx+1,
    // sigma1^2+sigma2^2 = (cs - cx^2 - cy^2)/4, sigma12 = (cp - cx*cy)/4.
    const float C1 = 1.0e-4f;
    const float C2 = 9.0e-4f;
    float nn[8], dd[8];
    #pragma unroll
    for (int j = 0; j < 8; ++j) {
        f4 v = A[j];
        float t1 = v.x + 1.f, t2 = v.y + 1.f;    // 2*mu1, 2*mu2
        float num1 = fmaf(t1 * t2, 0.5f, C1);    // 2*mu1*mu2 + C1
        float den1 = fmaf(fmaf(t2, t2, t1 * t1), 0.25f, C1);
        float num2 = fmaf(v.w - v.x * v.y, 0.5f, C2);   // 2*sigma12 + C2
        float den2 = fmaf(v.z - fmaf(v.x, v.x, v.y * v.y), 0.25f, C2);
        bool valid = (R0 + rb + j < OH) & (C0 + c < OW);
        nn[j] = valid ? num1 * num2 : 0.f;
        dd[j] = valid ? den1 * den2 : 1.f;
    }
    // 2 divides for 8 outputs: common denominator per group of 4
    // (dd >= C1*C2 ~ 1e-7; 4-products >= ~6e-29 stay normal in f32)
    double tsum = 0.0;
    #pragma unroll
    for (int g = 0; g < 8; g += 4) {
        float d01 = dd[g] * dd[g + 1], d23 = dd[g + 2] * dd[g + 3];
        float s01 = fmaf(nn[g], dd[g + 1], nn[g + 1] * dd[g]);
        float s23 = fmaf(nn[g + 2], dd[g + 3], nn[g + 3] * dd[g + 2]);
        tsum += (double)(fmaf(s01, d23, s23 * d01) / (d01 * d23));
    }

    // block reduction (double) + one f64 atomic into a strided slot
    #pragma unroll
    for (int off = 32; off > 0; off >>= 1)
        tsum += __shfl_down(tsum, off, 64);
    if ((tid & 63) == 0) wsum[tid >> 6] = tsum;
    __syncthreads();
    if (tid == 0) {
        int slot = (blockIdx.x + blockIdx.y * GX + blockIdx.z * GX * GY) & (NSLOT - 1);
        atomicAdd(&acc[slot * 8], wsum[0] + wsum[1] + wsum[2] + wsum[3]);
    }
}

__global__ void ssim_finalize(const double* __restrict__ acc,
                              float* __restrict__ out) {
    int lane = threadIdx.x;                      // 64 threads, one slot each
    double t = acc[lane * 8];
    #pragma unroll
    for (int off = 32; off > 0; off >>= 1)
        t += __shfl_down(t, off, 64);
    if (lane == 0)
        out[0] = (float)(t * (1.0 / (double)((long long)NC * OH * OW)));
}

extern "C" void kernel_launch(void* const* d_in, const int* in_sizes, int n_in,
                              void* d_out, int out_size, void* d_ws, size_t ws_size,
                              hipStream_t stream) {
    const float* X = (const float*)d_in[0];
    const float* Y = (const float*)d_in[1];
    float* out = (float*)d_out;
    double* acc = (double*)d_ws;                 // 64 slots x 64 B = 4 KB

    // d_ws is re-poisoned to 0xAA before every timed launch: zero the slots.
    hipMemsetAsync(d_ws, 0, NSLOT * 64, stream);

    // Gaussian weights (win=11, sigma=1.5), computed in f64, passed by value.
    GaussW gw;
    {
        double g[11], s = 0.0;
        for (int i = 0; i < 11; ++i) {
            double d = (double)(i - 5);
            g[i] = exp(-d * d / (2.0 * 1.5 * 1.5));
            s += g[i];
        }
        for (int i = 0; i < 11; ++i) gw.g[i] = (float)(g[i] / s);
    }

    dim3 grid(GX, GY, NC);
    ssim_kernel<<<grid, dim3(256), 0, stream>>>(X, Y, acc, gw);
    ssim_finalize<<<1, dim3(64), 0, stream>>>(acc, out);
}